// Round 9
// baseline (224.700 us; speedup 1.0000x reference)
//
#include <hip/hip_runtime.h>
#include <hip/hip_bf16.h>
#include <math.h>

#define HW 3136
#define NC 192
#define NHEADS 6
#define IMG 56
#define NATT 486
#define YSTR 1152          // Y row: [0,192)=v, [192,1152)=att padded head*160 + k*16 + l
#define ATT_SCALE 0.17677669529663687f  // 32^-0.5

typedef __attribute__((ext_vector_type(8))) short short8;
typedef __attribute__((ext_vector_type(8))) unsigned short ushort8;
typedef __attribute__((ext_vector_type(4))) float float4v;

__device__ __forceinline__ float bf2f(unsigned short u) {
    unsigned int x = ((unsigned int)u) << 16;
    return __builtin_bit_cast(float, x);
}
__device__ __forceinline__ unsigned short f2bf(float f) {
    __hip_bfloat16 h = __float2bfloat16(f);
    return __builtin_bit_cast(unsigned short, h);
}
__device__ __forceinline__ void gload_lds16(const void* g, void* l) {
    __builtin_amdgcn_global_load_lds((const __attribute__((address_space(1))) void*)g,
                                     (__attribute__((address_space(3))) void*)l, 16, 0, 0);
}

// x [16][192][3136] fp32 -> xt [50176][192] bf16 (channels-last). grid (784,3), block 256.
__global__ __launch_bounds__(256) void transpose_x(const float* __restrict__ x,
                                                   unsigned short* __restrict__ xt)
{
    __shared__ float tile[64][65];
    int bx = blockIdx.x;
    int n = (bx * 64) / HW;
    int hw0 = (bx * 64) % HW;
    int c0 = blockIdx.y * 64;
    int tl = threadIdx.x & 63, tg = threadIdx.x >> 6;
    const float* xn = x + (size_t)n * NC * HW;
#pragma unroll
    for (int i = 0; i < 16; ++i)
        tile[tg * 16 + i][tl] = xn[(size_t)(c0 + tg * 16 + i) * HW + hw0 + tl];
    __syncthreads();
    unsigned short* xp = xt + ((size_t)n * HW + hw0) * NC + c0;
#pragma unroll
    for (int i = 0; i < 16; ++i) {
        int hwr = tg * 16 + i;
        xp[(size_t)hwr * NC + tl] = f2bf(tile[tl][hwr]);
    }
}

// Weight prep: Wall[1152][192] = [Wv^T ; Wa^T permuted+padded], ball[1152] bias,
// Wpt[192][192] = Wp^T. grid 864, block 256.
__global__ __launch_bounds__(256) void prep_weights(
    const float* __restrict__ Wv, const float* __restrict__ Wa, const float* __restrict__ Wp,
    const float* __restrict__ ba,
    unsigned short* __restrict__ Wall, unsigned short* __restrict__ Wpt,
    float* __restrict__ ball)
{
    int idx = blockIdx.x * 256 + threadIdx.x;
    if (idx < 36864) {
        int d = idx / 192, k = idx - d * 192;
        Wpt[idx] = f2bf(Wp[(size_t)k * NC + d]);
    }
    if (idx < 221184) {                       // 1152*192
        int d = idx / 192, k = idx - d * 192;
        unsigned short val;
        float bv = 0.f;
        if (d < 192) {
            val = f2bf(Wv[(size_t)k * NC + d]);
        } else {
            int dp = d - 192;
            int head = dp / 160, rr = dp - head * 160, k9 = rr >> 4, l = rr & 15;
            bool valid = (k9 < 9) && (l < 9);
            int src = head * 81 + k9 * 9 + l;
            val = valid ? f2bf(Wa[(size_t)k * NATT + src]) : (unsigned short)0;
            bv = valid ? ba[src] : 0.f;
        }
        Wall[idx] = val;
        if (k == 0) ball[d] = bv;
    }
}

// Y[row][col] = sum_k xt[row][k]*Wall[col][k] + ball[col], bf16 out.
// 128x128 tile, 4 waves of 64x64 (4x4 acc), K=192 in 6 dbuf steps, glds16 staging.
// grid (9, 392) — col-tile fast so A row-tile stays L2-resident across its 9 blocks.
__global__ __launch_bounds__(256) void gemm_big(
    const unsigned short* __restrict__ A, const unsigned short* __restrict__ W,
    const float* __restrict__ ball, unsigned short* __restrict__ Y)
{
    __shared__ __align__(16) unsigned short As[2][4096];
    __shared__ __align__(16) unsigned short Bs[2][4096];
    int t = threadIdx.x, lane = t & 63, wave = t >> 6;
    int col0 = blockIdx.x * 128, row0 = blockIdx.y * 128;
    int fr = lane & 15, fq = lane >> 4;
    int wm = (wave >> 1) * 64, wn = (wave & 1) * 64;
    int srow = lane >> 2;          // 0..15
    int soff = (lane & 3) * 16;    // byte offset within a 64-B k-row chunk
    const char* Ab = (const char*)A;
    const char* Wb = (const char*)W;

    float4v acc[4][4] = {};

#define STAGE_BIG(buf, k0)                                                        \
    {                                                                             \
        _Pragma("unroll")                                                         \
        for (int i = 0; i < 2; ++i) {                                             \
            int j = wave * 2 + i;                                                 \
            gload_lds16(Ab + (size_t)(row0 + j * 16 + srow) * 384 + (k0)*2 + soff,\
                        (char*)As[buf] + j * 1024);                               \
            gload_lds16(Wb + (size_t)(col0 + j * 16 + srow) * 384 + (k0)*2 + soff,\
                        (char*)Bs[buf] + j * 1024);                               \
        }                                                                         \
    }

    STAGE_BIG(0, 0);
    for (int s = 0; s < 6; ++s) {
        if (s < 5) STAGE_BIG((s + 1) & 1, (s + 1) * 32);
        __syncthreads();
        int buf = s & 1;
        short8 af[4], bf[4];
#pragma unroll
        for (int mi = 0; mi < 4; ++mi)
            af[mi] = *(const short8*)((const char*)As[buf] + (wm + mi * 16 + fr) * 64 + fq * 16);
#pragma unroll
        for (int ni = 0; ni < 4; ++ni)
            bf[ni] = *(const short8*)((const char*)Bs[buf] + (wn + ni * 16 + fr) * 64 + fq * 16);
#pragma unroll
        for (int mi = 0; mi < 4; ++mi)
#pragma unroll
            for (int ni = 0; ni < 4; ++ni)
                acc[mi][ni] = __builtin_amdgcn_mfma_f32_16x16x32_bf16(
                    af[mi], bf[ni], acc[mi][ni], 0, 0, 0);
        __syncthreads();
    }

#pragma unroll
    for (int ni = 0; ni < 4; ++ni) {
        int col = col0 + wn + ni * 16 + fr;
        float b = ball[col];
#pragma unroll
        for (int mi = 0; mi < 4; ++mi) {
            int row = row0 + wm + mi * 16 + fq * 4;
#pragma unroll
            for (int r = 0; r < 4; ++r)
                Y[(size_t)(row + r) * YSTR + col] = f2bf(acc[mi][ni][r] + b);
        }
    }
#undef STAGE_BIG
}

// out[img][m][phw] = sum_k Wpt[m][k]*fold[n][k] + bias[m]; 64(m) x 256(n) tile.
// grid (196, 3), block 256, 4 waves each 64x64.
__global__ __launch_bounds__(256) void gemm_small(
    const unsigned short* __restrict__ A,   // Wpt [192][192]
    const unsigned short* __restrict__ B,   // fold [50176][192]
    const float* __restrict__ bias, float* __restrict__ out)
{
    __shared__ __align__(16) unsigned short As[2][2048];
    __shared__ __align__(16) unsigned short Bs[2][8192];
    int t = threadIdx.x, lane = t & 63, wave = t >> 6;
    int n0 = blockIdx.x * 256, m0 = blockIdx.y * 64;
    int fr = lane & 15, fq = lane >> 4;
    int srow = lane >> 2, soff = (lane & 3) * 16;
    const char* Ab = (const char*)A;
    const char* Bb = (const char*)B;

    float4v acc[4][4] = {};

#define STAGE_SMALL(buf, k0)                                                      \
    {                                                                             \
        gload_lds16(Ab + (size_t)(m0 + wave * 16 + srow) * 384 + (k0)*2 + soff,   \
                    (char*)As[buf] + wave * 1024);                                \
        _Pragma("unroll")                                                         \
        for (int i = 0; i < 4; ++i) {                                             \
            int j = wave * 4 + i;                                                 \
            gload_lds16(Bb + (size_t)(n0 + j * 16 + srow) * 384 + (k0)*2 + soff,  \
                        (char*)Bs[buf] + j * 1024);                               \
        }                                                                         \
    }

    STAGE_SMALL(0, 0);
    for (int s = 0; s < 6; ++s) {
        if (s < 5) STAGE_SMALL((s + 1) & 1, (s + 1) * 32);
        __syncthreads();
        int buf = s & 1;
        short8 af[4], bf[4];
#pragma unroll
        for (int mi = 0; mi < 4; ++mi)
            af[mi] = *(const short8*)((const char*)As[buf] + (mi * 16 + fr) * 64 + fq * 16);
#pragma unroll
        for (int ni = 0; ni < 4; ++ni)
            bf[ni] = *(const short8*)((const char*)Bs[buf] + (wave * 64 + ni * 16 + fr) * 64 + fq * 16);
#pragma unroll
        for (int mi = 0; mi < 4; ++mi)
#pragma unroll
            for (int ni = 0; ni < 4; ++ni)
                acc[mi][ni] = __builtin_amdgcn_mfma_f32_16x16x32_bf16(
                    af[mi], bf[ni], acc[mi][ni], 0, 0, 0);
        __syncthreads();
    }

#pragma unroll
    for (int ni = 0; ni < 4; ++ni) {
        int n = n0 + wave * 64 + ni * 16 + fr;
        int img = n / HW, phw = n - img * HW;
        float* op = out + (size_t)img * (NC * HW) + phw;
#pragma unroll
        for (int mi = 0; mi < 4; ++mi) {
            int m = m0 + mi * 16 + fq * 4;
#pragma unroll
            for (int r = 0; r < 4; ++r)
                op[(size_t)(m + r) * HW] = acc[mi][ni][r] + bias[m + r];
        }
    }
#undef STAGE_SMALL
}

// Fused softmax + weight-combine (25-tap) + aggregation (R7 structure).
// Block = 32 positions x 6 heads. Phase 1: threads 0..191 full softmax ->
// wc[25] to LDS. Phase 2: 768 items (pos,head,quarter), 3/thread, coalesced
// v reads from Y cols [0,192), wc broadcast from LDS.
__global__ __launch_bounds__(256) void fused_att_agg(
    const unsigned short* __restrict__ Y, unsigned short* __restrict__ fold)
{
    __shared__ float swc[192 * 25];
    int t = threadIdx.x;
    int pos_base = blockIdx.x * 32;

    if (t < 192) {
        int pos = t / 6, head = t - pos * 6;
        int rem = pos_base + pos;
        int hw = rem % HW;
        int h = hw / IMG, w = hw % IMG;
        const unsigned short* attn = Y + (size_t)rem * YSTR + 192 + head * 160;
        float wc[25];
#pragma unroll
        for (int d = 0; d < 25; ++d) wc[d] = 0.f;
#pragma unroll
        for (int k = 0; k < 9; ++k) {
            const int oky = k / 3 - 1, okx = k % 3 - 1;
            int hh = h - oky, ww = w - okx;
            if (hh < 0 || hh >= IMG || ww < 0 || ww >= IMG) continue;
            const unsigned short* ap = attn - (ptrdiff_t)(oky * IMG + okx) * YSTR + k * 16;
            ushort8 a8 = *(const ushort8*)ap;       // 16-B aligned
            float a[9];
#pragma unroll
            for (int l = 0; l < 8; ++l) a[l] = bf2f(a8[l]);
            a[8] = bf2f(ap[8]);
            float m = -1e30f;
#pragma unroll
            for (int l = 0; l < 9; ++l) m = fmaxf(m, a[l]);
            float s = 0.f;
#pragma unroll
            for (int l = 0; l < 9; ++l) {
                a[l] = __expf((a[l] - m) * ATT_SCALE);
                s += a[l];
            }
            float r = 1.f / s;
#pragma unroll
            for (int l = 0; l < 9; ++l) {
                const int dy = (l / 3 - 1) - oky + 2;
                const int dx = (l % 3 - 1) - okx + 2;
                wc[dy * 5 + dx] += a[l] * r;
            }
        }
        float* o = swc + t * 25;
#pragma unroll
        for (int d = 0; d < 25; ++d) o[d] = wc[d];
    }
    __syncthreads();

#pragma unroll
    for (int i = 0; i < 3; ++i) {
        int item = i * 256 + t;                 // 0..767
        int pos = item / 24, sub = item - pos * 24;
        int head = sub >> 2, q8 = sub & 3;
        int rem = pos_base + pos;
        int hw = rem % HW;
        int h = hw / IMG, w = hw % IMG;
        const float* wp = swc + (pos * 6 + head) * 25;
        const unsigned short* vb = Y + (size_t)rem * YSTR + head * 32 + q8 * 8;
        float acc[8];
#pragma unroll
        for (int j = 0; j < 8; ++j) acc[j] = 0.f;
        if (h >= 2 && h < IMG - 2 && w >= 2 && w < IMG - 2) {
#pragma unroll
            for (int d = 0; d < 25; ++d) {
                const int dy = d / 5 - 2, dx = d % 5 - 2;
                float wf = wp[d];
                ushort8 vv = *(const ushort8*)(vb + (dy * IMG + dx) * YSTR);
#pragma unroll
                for (int j = 0; j < 8; ++j)
                    acc[j] += wf * bf2f(vv[j]);
            }
        } else {
#pragma unroll
            for (int d = 0; d < 25; ++d) {
                const int dy = d / 5 - 2, dx = d % 5 - 2;
                int hh = h + dy, ww = w + dx;
                bool ok = (hh >= 0) & (hh < IMG) & (ww >= 0) & (ww < IMG);
                float wf = ok ? wp[d] : 0.f;
                const unsigned short* vp = vb + (ok ? (dy * IMG + dx) * YSTR : 0);
                ushort8 vv = *(const ushort8*)vp;
#pragma unroll
                for (int j = 0; j < 8; ++j)
                    acc[j] += wf * bf2f(vv[j]);
            }
        }
        unsigned short* fo = fold + (size_t)rem * NC + head * 32 + q8 * 8;
        ushort8 ov;
#pragma unroll
        for (int j = 0; j < 8; ++j) ov[j] = f2bf(acc[j]);
        *(ushort8*)fo = ov;
    }
}

extern "C" void kernel_launch(void* const* d_in, const int* in_sizes, int n_in,
                              void* d_out, int out_size, void* d_ws, size_t ws_size,
                              hipStream_t stream)
{
    const float* x  = (const float*)d_in[0];
    const float* Wv = (const float*)d_in[1];
    const float* Wa = (const float*)d_in[2];
    const float* ba = (const float*)d_in[3];
    const float* Wp = (const float*)d_in[4];
    const float* bp = (const float*)d_in[5];
    float* out = (float*)d_out;

    unsigned short* xt    = (unsigned short*)d_ws;       // 50176*192 (also reused as fold)
    unsigned short* Y     = xt + 9633792;                // 50176*1152
    unsigned short* Wall  = Y + 57802752;                // 1152*192
    unsigned short* Wpt   = Wall + 221184;               // 192*192
    float*          ball  = (float*)(Wpt + 36864);       // 1152 floats
    unsigned short* foldb = xt;                          // xt dead after gemm_big

    dim3 blk(256);
    prep_weights<<<864, blk, 0, stream>>>(Wv, Wa, Wp, ba, Wall, Wpt, ball);
    transpose_x<<<dim3(784, 3), blk, 0, stream>>>(x, xt);
    gemm_big<<<dim3(9, 392), blk, 0, stream>>>(xt, Wall, ball, Y);
    fused_att_agg<<<1568, blk, 0, stream>>>(Y, foldb);
    gemm_small<<<dim3(196, 3), blk, 0, stream>>>(Wpt, foldb, bp, out);
}

// Round 10
// 220.755 us; speedup vs baseline: 1.0179x; 1.0179x over previous
//
#include <hip/hip_runtime.h>
#include <hip/hip_bf16.h>
#include <math.h>

#define HW 3136
#define NC 192
#define NHEADS 6
#define IMG 56
#define NATT 486
#define YSTR 1152          // Y row: [0,192)=v, [192,1152)=att padded head*160 + k*16 + l
#define FOLD_STR 200       // LDS fold tile row stride (shorts)
#define ATT_SCALE 0.17677669529663687f  // 32^-0.5

typedef __attribute__((ext_vector_type(8))) short short8;
typedef __attribute__((ext_vector_type(8))) unsigned short ushort8;
typedef __attribute__((ext_vector_type(4))) float float4v;
typedef __attribute__((ext_vector_type(2))) float float2v;
typedef __attribute__((ext_vector_type(4))) unsigned int uint4v;

__device__ __forceinline__ float bf2f(unsigned short u) {
    unsigned int x = ((unsigned int)u) << 16;
    return __builtin_bit_cast(float, x);
}
__device__ __forceinline__ unsigned short f2bf(float f) {
    __hip_bfloat16 h = __float2bfloat16(f);
    return __builtin_bit_cast(unsigned short, h);
}
__device__ __forceinline__ void gload_lds16(const void* g, void* l) {
    __builtin_amdgcn_global_load_lds((const __attribute__((address_space(1))) void*)g,
                                     (__attribute__((address_space(3))) void*)l, 16, 0, 0);
}

// x [16][192][3136] fp32 -> xt [50176][192] bf16 (channels-last). grid (784,3), block 256.
__global__ __launch_bounds__(256) void transpose_x(const float* __restrict__ x,
                                                   unsigned short* __restrict__ xt)
{
    __shared__ float tile[64][65];
    int bx = blockIdx.x;
    int n = (bx * 64) / HW;
    int hw0 = (bx * 64) % HW;
    int c0 = blockIdx.y * 64;
    int tl = threadIdx.x & 63, tg = threadIdx.x >> 6;
    const float* xn = x + (size_t)n * NC * HW;
#pragma unroll
    for (int i = 0; i < 16; ++i)
        tile[tg * 16 + i][tl] = xn[(size_t)(c0 + tg * 16 + i) * HW + hw0 + tl];
    __syncthreads();
    unsigned short* xp = xt + ((size_t)n * HW + hw0) * NC + c0;
#pragma unroll
    for (int i = 0; i < 16; ++i) {
        int hwr = tg * 16 + i;
        xp[(size_t)hwr * NC + tl] = f2bf(tile[tl][hwr]);
    }
}

// Weight prep: Wall[1152][192] = [Wv^T ; Wa^T permuted+padded], ball[1152] bias,
// Wpt[192][192] = Wp^T. grid 864, block 256.
__global__ __launch_bounds__(256) void prep_weights(
    const float* __restrict__ Wv, const float* __restrict__ Wa, const float* __restrict__ Wp,
    const float* __restrict__ ba,
    unsigned short* __restrict__ Wall, unsigned short* __restrict__ Wpt,
    float* __restrict__ ball)
{
    int idx = blockIdx.x * 256 + threadIdx.x;
    if (idx < 36864) {
        int d = idx / 192, k = idx - d * 192;
        Wpt[idx] = f2bf(Wp[(size_t)k * NC + d]);
    }
    if (idx < 221184) {                       // 1152*192
        int d = idx / 192, k = idx - d * 192;
        unsigned short val;
        float bv = 0.f;
        if (d < 192) {
            val = f2bf(Wv[(size_t)k * NC + d]);
        } else {
            int dp = d - 192;
            int head = dp / 160, rr = dp - head * 160, k9 = rr >> 4, l = rr & 15;
            bool valid = (k9 < 9) && (l < 9);
            int src = head * 81 + k9 * 9 + l;
            val = valid ? f2bf(Wa[(size_t)k * NATT + src]) : (unsigned short)0;
            bv = valid ? ba[src] : 0.f;
        }
        Wall[idx] = val;
        if (k == 0) ball[d] = bv;
    }
}

// Y[row][col] = sum_k xt[row][k]*Wall[col][k] + ball[col], bf16 out.
// 128x128 tile, 4 waves of 64x64 (4x4 acc), K=192 in 6 dbuf steps, glds16 staging.
// grid (9, 392).
__global__ __launch_bounds__(256) void gemm_big(
    const unsigned short* __restrict__ A, const unsigned short* __restrict__ W,
    const float* __restrict__ ball, unsigned short* __restrict__ Y)
{
    __shared__ __align__(16) unsigned short As[2][4096];
    __shared__ __align__(16) unsigned short Bs[2][4096];
    int t = threadIdx.x, lane = t & 63, wave = t >> 6;
    int col0 = blockIdx.x * 128, row0 = blockIdx.y * 128;
    int fr = lane & 15, fq = lane >> 4;
    int wm = (wave >> 1) * 64, wn = (wave & 1) * 64;
    int srow = lane >> 2;          // 0..15
    int soff = (lane & 3) * 16;    // byte offset within a 64-B k-row chunk
    const char* Ab = (const char*)A;
    const char* Wb = (const char*)W;

    float4v acc[4][4] = {};

#define STAGE_BIG(buf, k0)                                                        \
    {                                                                             \
        _Pragma("unroll")                                                         \
        for (int i = 0; i < 2; ++i) {                                             \
            int j = wave * 2 + i;                                                 \
            gload_lds16(Ab + (size_t)(row0 + j * 16 + srow) * 384 + (k0)*2 + soff,\
                        (char*)As[buf] + j * 1024);                               \
            gload_lds16(Wb + (size_t)(col0 + j * 16 + srow) * 384 + (k0)*2 + soff,\
                        (char*)Bs[buf] + j * 1024);                               \
        }                                                                         \
    }

    STAGE_BIG(0, 0);
    for (int s = 0; s < 6; ++s) {
        if (s < 5) STAGE_BIG((s + 1) & 1, (s + 1) * 32);
        __syncthreads();
        int buf = s & 1;
        short8 af[4], bf[4];
#pragma unroll
        for (int mi = 0; mi < 4; ++mi)
            af[mi] = *(const short8*)((const char*)As[buf] + (wm + mi * 16 + fr) * 64 + fq * 16);
#pragma unroll
        for (int ni = 0; ni < 4; ++ni)
            bf[ni] = *(const short8*)((const char*)Bs[buf] + (wn + ni * 16 + fr) * 64 + fq * 16);
#pragma unroll
        for (int mi = 0; mi < 4; ++mi)
#pragma unroll
            for (int ni = 0; ni < 4; ++ni)
                acc[mi][ni] = __builtin_amdgcn_mfma_f32_16x16x32_bf16(
                    af[mi], bf[ni], acc[mi][ni], 0, 0, 0);
        __syncthreads();
    }

#pragma unroll
    for (int ni = 0; ni < 4; ++ni) {
        int col = col0 + wn + ni * 16 + fr;
        float b = ball[col];
#pragma unroll
        for (int mi = 0; mi < 4; ++mi) {
            int row = row0 + wm + mi * 16 + fq * 4;
#pragma unroll
            for (int r = 0; r < 4; ++r)
                Y[(size_t)(row + r) * YSTR + col] = f2bf(acc[mi][ni][r] + b);
        }
    }
#undef STAGE_BIG
}

// Fused softmax + weight-combine + aggregation + OUTPUT PROJECTION.
// Block = 32 positions x 6 heads.
// Phase 1: threads 0..191 full softmax -> wc[25] to LDS swc.
// Phase 2: 768 items (pos,head,quarter), 3/thread, pk-FMA agg -> fold tile in LDS.
// Phase 3: out[cout][pos] = sum_c Wpt[cout][c]*fold[pos][c] + bp[cout] via MFMA,
//          per wave 48 couts x 32 pos, fp32 coalesced stores.
__global__ __launch_bounds__(256) void fused_att_agg_out(
    const unsigned short* __restrict__ Y, const unsigned short* __restrict__ Wpt,
    const float* __restrict__ bp, float* __restrict__ out)
{
    __shared__ float swc[192 * 25];                              // 19200 B
    __shared__ __align__(16) unsigned short fl[32 * FOLD_STR];   // 12800 B
    int t = threadIdx.x;
    int pos_base = blockIdx.x * 32;

    // ---- phase 1: stencil weights ----
    if (t < 192) {
        int pos = t / 6, head = t - pos * 6;
        int rem = pos_base + pos;
        int hw = rem % HW;
        int h = hw / IMG, w = hw % IMG;
        const unsigned short* attn = Y + (size_t)rem * YSTR + 192 + head * 160;
        float wc[25];
#pragma unroll
        for (int d = 0; d < 25; ++d) wc[d] = 0.f;
#pragma unroll
        for (int k = 0; k < 9; ++k) {
            const int oky = k / 3 - 1, okx = k % 3 - 1;
            int hh = h - oky, ww = w - okx;
            if (hh < 0 || hh >= IMG || ww < 0 || ww >= IMG) continue;
            const unsigned short* ap = attn - (ptrdiff_t)(oky * IMG + okx) * YSTR + k * 16;
            ushort8 a8 = *(const ushort8*)ap;
            float a[9];
#pragma unroll
            for (int l = 0; l < 8; ++l) a[l] = bf2f(a8[l]);
            a[8] = bf2f(ap[8]);
            float m = -1e30f;
#pragma unroll
            for (int l = 0; l < 9; ++l) m = fmaxf(m, a[l]);
            float s = 0.f;
#pragma unroll
            for (int l = 0; l < 9; ++l) {
                a[l] = __expf((a[l] - m) * ATT_SCALE);
                s += a[l];
            }
            float r = 1.f / s;
#pragma unroll
            for (int l = 0; l < 9; ++l) {
                const int dy = (l / 3 - 1) - oky + 2;
                const int dx = (l % 3 - 1) - okx + 2;
                wc[dy * 5 + dx] += a[l] * r;
            }
        }
        float* o = swc + t * 25;
#pragma unroll
        for (int d = 0; d < 25; ++d) o[d] = wc[d];
    }
    __syncthreads();

    // ---- phase 2: aggregate -> fold tile in LDS (packed FMA) ----
#pragma unroll
    for (int i = 0; i < 3; ++i) {
        int item = i * 256 + t;                 // 0..767
        int pos = item / 24, sub = item - pos * 24;
        int head = sub >> 2, q8 = sub & 3;
        int rem = pos_base + pos;
        int hw = rem % HW;
        int h = hw / IMG, w = hw % IMG;
        const float* wp = swc + (pos * 6 + head) * 25;
        const unsigned short* vb = Y + (size_t)rem * YSTR + head * 32 + q8 * 8;
        float2v acc2[4] = {};
        if (h >= 2 && h < IMG - 2 && w >= 2 && w < IMG - 2) {
#pragma unroll
            for (int d = 0; d < 25; ++d) {
                const int dy = d / 5 - 2, dx = d % 5 - 2;
                float wf = wp[d];
                float2v wf2 = {wf, wf};
                ushort8 vv = *(const ushort8*)(vb + (dy * IMG + dx) * YSTR);
                uint4v uv = __builtin_bit_cast(uint4v, vv);
#pragma unroll
                for (int j = 0; j < 4; ++j) {
                    unsigned int u = uv[j];
                    float2v val = {__builtin_bit_cast(float, u << 16),
                                   __builtin_bit_cast(float, u & 0xFFFF0000u)};
                    acc2[j] += wf2 * val;
                }
            }
        } else {
#pragma unroll
            for (int d = 0; d < 25; ++d) {
                const int dy = d / 5 - 2, dx = d % 5 - 2;
                int hh = h + dy, ww = w + dx;
                bool ok = (hh >= 0) & (hh < IMG) & (ww >= 0) & (ww < IMG);
                float wf = ok ? wp[d] : 0.f;
                float2v wf2 = {wf, wf};
                const unsigned short* vp = vb + (ok ? (dy * IMG + dx) * YSTR : 0);
                ushort8 vv = *(const ushort8*)vp;
                uint4v uv = __builtin_bit_cast(uint4v, vv);
#pragma unroll
                for (int j = 0; j < 4; ++j) {
                    unsigned int u = uv[j];
                    float2v val = {__builtin_bit_cast(float, u << 16),
                                   __builtin_bit_cast(float, u & 0xFFFF0000u)};
                    acc2[j] += wf2 * val;
                }
            }
        }
        ushort8 ov;
#pragma unroll
        for (int j = 0; j < 4; ++j) {
            ov[2 * j]     = f2bf(acc2[j][0]);
            ov[2 * j + 1] = f2bf(acc2[j][1]);
        }
        *(ushort8*)&fl[pos * FOLD_STR + head * 32 + q8 * 8] = ov;
    }
    __syncthreads();

    // ---- phase 3: output projection via MFMA ----
    {
        int lane = t & 63, wave = t >> 6;
        int fr = lane & 15, fq = lane >> 4;
        int m0w = wave * 48;
        float4v acc[3][2] = {};
        for (int k0 = 0; k0 < 192; k0 += 32) {
            short8 af[3], bf[2];
#pragma unroll
            for (int mi = 0; mi < 3; ++mi)
                af[mi] = *(const short8*)(Wpt + (size_t)(m0w + mi * 16 + fr) * 192 + k0 + fq * 8);
#pragma unroll
            for (int ni = 0; ni < 2; ++ni)
                bf[ni] = *(const short8*)&fl[(ni * 16 + fr) * FOLD_STR + k0 + fq * 8];
#pragma unroll
            for (int mi = 0; mi < 3; ++mi)
#pragma unroll
                for (int ni = 0; ni < 2; ++ni)
                    acc[mi][ni] = __builtin_amdgcn_mfma_f32_16x16x32_bf16(
                        af[mi], bf[ni], acc[mi][ni], 0, 0, 0);
        }
        int img = pos_base / HW, hw0 = pos_base % HW;
        float* ob = out + (size_t)img * (NC * HW) + hw0;
#pragma unroll
        for (int mi = 0; mi < 3; ++mi)
#pragma unroll
            for (int ni = 0; ni < 2; ++ni)
#pragma unroll
                for (int r = 0; r < 4; ++r) {
                    int cout = m0w + mi * 16 + fq * 4 + r;
                    ob[(size_t)cout * HW + ni * 16 + fr] = acc[mi][ni][r] + bp[cout];
                }
    }
}

extern "C" void kernel_launch(void* const* d_in, const int* in_sizes, int n_in,
                              void* d_out, int out_size, void* d_ws, size_t ws_size,
                              hipStream_t stream)
{
    const float* x  = (const float*)d_in[0];
    const float* Wv = (const float*)d_in[1];
    const float* Wa = (const float*)d_in[2];
    const float* ba = (const float*)d_in[3];
    const float* Wp = (const float*)d_in[4];
    const float* bp = (const float*)d_in[5];
    float* out = (float*)d_out;

    unsigned short* xt    = (unsigned short*)d_ws;       // 50176*192
    unsigned short* Y     = xt + 9633792;                // 50176*1152
    unsigned short* Wall  = Y + 57802752;                // 1152*192
    unsigned short* Wpt   = Wall + 221184;               // 192*192
    float*          ball  = (float*)(Wpt + 36864);       // 1152 floats

    dim3 blk(256);
    prep_weights<<<864, blk, 0, stream>>>(Wv, Wa, Wp, ba, Wall, Wpt, ball);
    transpose_x<<<dim3(784, 3), blk, 0, stream>>>(x, xt);
    gemm_big<<<dim3(9, 392), blk, 0, stream>>>(xt, Wall, ball, Y);
    fused_att_agg_out<<<1568, blk, 0, stream>>>(Y, Wpt, bp, out);
}

// Round 11
// 209.961 us; speedup vs baseline: 1.0702x; 1.0514x over previous
//
#include <hip/hip_runtime.h>
#include <hip/hip_bf16.h>
#include <math.h>

#define HW 3136
#define NC 192
#define NHEADS 6
#define IMG 56
#define NATT 486
#define YSTR 768           // Y row: [0,192)=v, [192,768)=att head*96 + k*10 + l
#define ATT_SCALE 0.17677669529663687f  // 32^-0.5

typedef __attribute__((ext_vector_type(8))) short short8;
typedef __attribute__((ext_vector_type(8))) unsigned short ushort8;
typedef __attribute__((ext_vector_type(4))) float float4v;

__device__ __forceinline__ float bf2f(unsigned short u) {
    unsigned int x = ((unsigned int)u) << 16;
    return __builtin_bit_cast(float, x);
}
__device__ __forceinline__ unsigned short f2bf(float f) {
    __hip_bfloat16 h = __float2bfloat16(f);
    return __builtin_bit_cast(unsigned short, h);
}
__device__ __forceinline__ void gload_lds16(const void* g, void* l) {
    __builtin_amdgcn_global_load_lds((const __attribute__((address_space(1))) void*)g,
                                     (__attribute__((address_space(3))) void*)l, 16, 0, 0);
}

// x [16][192][3136] fp32 -> xt [50176][192] bf16 (channels-last). grid (784,3), block 256.
__global__ __launch_bounds__(256) void transpose_x(const float* __restrict__ x,
                                                   unsigned short* __restrict__ xt)
{
    __shared__ float tile[64][65];
    int bx = blockIdx.x;
    int n = (bx * 64) / HW;
    int hw0 = (bx * 64) % HW;
    int c0 = blockIdx.y * 64;
    int tl = threadIdx.x & 63, tg = threadIdx.x >> 6;
    const float* xn = x + (size_t)n * NC * HW;
#pragma unroll
    for (int i = 0; i < 16; ++i)
        tile[tg * 16 + i][tl] = xn[(size_t)(c0 + tg * 16 + i) * HW + hw0 + tl];
    __syncthreads();
    unsigned short* xp = xt + ((size_t)n * HW + hw0) * NC + c0;
#pragma unroll
    for (int i = 0; i < 16; ++i) {
        int hwr = tg * 16 + i;
        xp[(size_t)hwr * NC + tl] = f2bf(tile[tl][hwr]);
    }
}

// Weight prep: Wall[768][192] = [Wv^T ; Wa^T permuted, stride 10], ball[768],
// Wpt[192][192] = Wp^T. grid 576, block 256.
__global__ __launch_bounds__(256) void prep_weights(
    const float* __restrict__ Wv, const float* __restrict__ Wa, const float* __restrict__ Wp,
    const float* __restrict__ ba,
    unsigned short* __restrict__ Wall, unsigned short* __restrict__ Wpt,
    float* __restrict__ ball)
{
    int idx = blockIdx.x * 256 + threadIdx.x;
    if (idx < 36864) {
        int d = idx / 192, k = idx - d * 192;
        Wpt[idx] = f2bf(Wp[(size_t)k * NC + d]);
    }
    if (idx < 147456) {                       // 768*192
        int d = idx / 192, k = idx - d * 192;
        unsigned short val;
        float bv = 0.f;
        if (d < 192) {
            val = f2bf(Wv[(size_t)k * NC + d]);
        } else {
            int dp = d - 192;                 // 0..575
            int head = dp / 96, rr = dp - head * 96;
            int k9 = rr / 10, l = rr - k9 * 10;
            bool valid = (k9 < 9) && (l < 9);
            int src = head * 81 + k9 * 9 + l;
            val = valid ? f2bf(Wa[(size_t)k * NATT + src]) : (unsigned short)0;
            bv = valid ? ba[src] : 0.f;
        }
        Wall[idx] = val;
        if (k == 0) ball[d] = bv;
    }
}

// Y[row][col] = sum_k xt[row][k]*Wall[col][k] + ball[col], bf16 out.
// 128x128 tile, 4 waves of 64x64 (4x4 acc), K=192 in 6 dbuf steps, glds16 staging.
// grid (6, 392).
__global__ __launch_bounds__(256) void gemm_big(
    const unsigned short* __restrict__ A, const unsigned short* __restrict__ W,
    const float* __restrict__ ball, unsigned short* __restrict__ Y)
{
    __shared__ __align__(16) unsigned short As[2][4096];
    __shared__ __align__(16) unsigned short Bs[2][4096];
    int t = threadIdx.x, lane = t & 63, wave = t >> 6;
    int col0 = blockIdx.x * 128, row0 = blockIdx.y * 128;
    int fr = lane & 15, fq = lane >> 4;
    int wm = (wave >> 1) * 64, wn = (wave & 1) * 64;
    int srow = lane >> 2;          // 0..15
    int soff = (lane & 3) * 16;    // byte offset within a 64-B k-row chunk
    const char* Ab = (const char*)A;
    const char* Wb = (const char*)W;

    float4v acc[4][4] = {};

#define STAGE_BIG(buf, k0)                                                        \
    {                                                                             \
        _Pragma("unroll")                                                         \
        for (int i = 0; i < 2; ++i) {                                             \
            int j = wave * 2 + i;                                                 \
            gload_lds16(Ab + (size_t)(row0 + j * 16 + srow) * 384 + (k0)*2 + soff,\
                        (char*)As[buf] + j * 1024);                               \
            gload_lds16(Wb + (size_t)(col0 + j * 16 + srow) * 384 + (k0)*2 + soff,\
                        (char*)Bs[buf] + j * 1024);                               \
        }                                                                         \
    }

    STAGE_BIG(0, 0);
    for (int s = 0; s < 6; ++s) {
        if (s < 5) STAGE_BIG((s + 1) & 1, (s + 1) * 32);
        __syncthreads();
        int buf = s & 1;
        short8 af[4], bf[4];
#pragma unroll
        for (int mi = 0; mi < 4; ++mi)
            af[mi] = *(const short8*)((const char*)As[buf] + (wm + mi * 16 + fr) * 64 + fq * 16);
#pragma unroll
        for (int ni = 0; ni < 4; ++ni)
            bf[ni] = *(const short8*)((const char*)Bs[buf] + (wn + ni * 16 + fr) * 64 + fq * 16);
#pragma unroll
        for (int mi = 0; mi < 4; ++mi)
#pragma unroll
            for (int ni = 0; ni < 4; ++ni)
                acc[mi][ni] = __builtin_amdgcn_mfma_f32_16x16x32_bf16(
                    af[mi], bf[ni], acc[mi][ni], 0, 0, 0);
        __syncthreads();
    }

#pragma unroll
    for (int ni = 0; ni < 4; ++ni) {
        int col = col0 + wn + ni * 16 + fr;
        float b = ball[col];
#pragma unroll
        for (int mi = 0; mi < 4; ++mi) {
            int row = row0 + wm + mi * 16 + fq * 4;
#pragma unroll
            for (int r = 0; r < 4; ++r)
                Y[(size_t)(row + r) * YSTR + col] = f2bf(acc[mi][ni][r] + b);
        }
    }
#undef STAGE_BIG
}

// out[img][m][phw] = sum_k Wpt[m][k]*fold[n][k] + bias[m]; 64(m) x 256(n) tile.
// grid (196, 3), block 256, 4 waves each 64x64.
__global__ __launch_bounds__(256) void gemm_small(
    const unsigned short* __restrict__ A,   // Wpt [192][192]
    const unsigned short* __restrict__ B,   // fold [50176][192]
    const float* __restrict__ bias, float* __restrict__ out)
{
    __shared__ __align__(16) unsigned short As[2][2048];
    __shared__ __align__(16) unsigned short Bs[2][8192];
    int t = threadIdx.x, lane = t & 63, wave = t >> 6;
    int n0 = blockIdx.x * 256, m0 = blockIdx.y * 64;
    int fr = lane & 15, fq = lane >> 4;
    int srow = lane >> 2, soff = (lane & 3) * 16;
    const char* Ab = (const char*)A;
    const char* Bb = (const char*)B;

    float4v acc[4][4] = {};

#define STAGE_SMALL(buf, k0)                                                      \
    {                                                                             \
        gload_lds16(Ab + (size_t)(m0 + wave * 16 + srow) * 384 + (k0)*2 + soff,   \
                    (char*)As[buf] + wave * 1024);                                \
        _Pragma("unroll")                                                         \
        for (int i = 0; i < 4; ++i) {                                             \
            int j = wave * 4 + i;                                                 \
            gload_lds16(Bb + (size_t)(n0 + j * 16 + srow) * 384 + (k0)*2 + soff,  \
                        (char*)Bs[buf] + j * 1024);                               \
        }                                                                         \
    }

    STAGE_SMALL(0, 0);
    for (int s = 0; s < 6; ++s) {
        if (s < 5) STAGE_SMALL((s + 1) & 1, (s + 1) * 32);
        __syncthreads();
        int buf = s & 1;
        short8 af[4], bf[4];
#pragma unroll
        for (int mi = 0; mi < 4; ++mi)
            af[mi] = *(const short8*)((const char*)As[buf] + (mi * 16 + fr) * 64 + fq * 16);
#pragma unroll
        for (int ni = 0; ni < 4; ++ni)
            bf[ni] = *(const short8*)((const char*)Bs[buf] + (wave * 64 + ni * 16 + fr) * 64 + fq * 16);
#pragma unroll
        for (int mi = 0; mi < 4; ++mi)
#pragma unroll
            for (int ni = 0; ni < 4; ++ni)
                acc[mi][ni] = __builtin_amdgcn_mfma_f32_16x16x32_bf16(
                    af[mi], bf[ni], acc[mi][ni], 0, 0, 0);
        __syncthreads();
    }

#pragma unroll
    for (int ni = 0; ni < 4; ++ni) {
        int n = n0 + wave * 64 + ni * 16 + fr;
        int img = n / HW, phw = n - img * HW;
        float* op = out + (size_t)img * (NC * HW) + phw;
#pragma unroll
        for (int mi = 0; mi < 4; ++mi) {
            int m = m0 + mi * 16 + fq * 4;
#pragma unroll
            for (int r = 0; r < 4; ++r)
                op[(size_t)(m + r) * HW] = acc[mi][ni][r] + bias[m + r];
        }
    }
#undef STAGE_SMALL
}

// Fused softmax + weight-combine (25-tap) + aggregation (R7/R8 structure).
// Block = 32 positions x 6 heads. Phase 1: threads 0..191 full softmax ->
// wc[25] to LDS. Phase 2: 768 items (pos,head,quarter), 3/thread, coalesced
// v reads from Y cols [0,192), wc broadcast from LDS.
// att rows are stride-10 shorts (dword-aligned) -> 16-B memcpy load + 1 scalar.
__global__ __launch_bounds__(256) void fused_att_agg(
    const unsigned short* __restrict__ Y, unsigned short* __restrict__ fold)
{
    __shared__ float swc[192 * 25];
    int t = threadIdx.x;
    int pos_base = blockIdx.x * 32;

    if (t < 192) {
        int pos = t / 6, head = t - pos * 6;
        int rem = pos_base + pos;
        int hw = rem % HW;
        int h = hw / IMG, w = hw % IMG;
        const unsigned short* attn = Y + (size_t)rem * YSTR + 192 + head * 96;
        float wc[25];
#pragma unroll
        for (int d = 0; d < 25; ++d) wc[d] = 0.f;
#pragma unroll
        for (int k = 0; k < 9; ++k) {
            const int oky = k / 3 - 1, okx = k % 3 - 1;
            int hh = h - oky, ww = w - okx;
            if (hh < 0 || hh >= IMG || ww < 0 || ww >= IMG) continue;
            const unsigned short* ap = attn - (ptrdiff_t)(oky * IMG + okx) * YSTR + k * 10;
            ushort8 a8;
            __builtin_memcpy(&a8, ap, 16);          // 4-B aligned, dwordx4-class load
            float a[9];
#pragma unroll
            for (int l = 0; l < 8; ++l) a[l] = bf2f(a8[l]);
            a[8] = bf2f(ap[8]);
            float m = -1e30f;
#pragma unroll
            for (int l = 0; l < 9; ++l) m = fmaxf(m, a[l]);
            float s = 0.f;
#pragma unroll
            for (int l = 0; l < 9; ++l) {
                a[l] = __expf((a[l] - m) * ATT_SCALE);
                s += a[l];
            }
            float r = 1.f / s;
#pragma unroll
            for (int l = 0; l < 9; ++l) {
                const int dy = (l / 3 - 1) - oky + 2;
                const int dx = (l % 3 - 1) - okx + 2;
                wc[dy * 5 + dx] += a[l] * r;
            }
        }
        float* o = swc + t * 25;
#pragma unroll
        for (int d = 0; d < 25; ++d) o[d] = wc[d];
    }
    __syncthreads();

#pragma unroll
    for (int i = 0; i < 3; ++i) {
        int item = i * 256 + t;                 // 0..767
        int pos = item / 24, sub = item - pos * 24;
        int head = sub >> 2, q8 = sub & 3;
        int rem = pos_base + pos;
        int hw = rem % HW;
        int h = hw / IMG, w = hw % IMG;
        const float* wp = swc + (pos * 6 + head) * 25;
        const unsigned short* vb = Y + (size_t)rem * YSTR + head * 32 + q8 * 8;
        float acc[8];
#pragma unroll
        for (int j = 0; j < 8; ++j) acc[j] = 0.f;
        if (h >= 2 && h < IMG - 2 && w >= 2 && w < IMG - 2) {
#pragma unroll
            for (int d = 0; d < 25; ++d) {
                const int dy = d / 5 - 2, dx = d % 5 - 2;
                float wf = wp[d];
                ushort8 vv = *(const ushort8*)(vb + (dy * IMG + dx) * YSTR);
#pragma unroll
                for (int j = 0; j < 8; ++j)
                    acc[j] += wf * bf2f(vv[j]);
            }
        } else {
#pragma unroll
            for (int d = 0; d < 25; ++d) {
                const int dy = d / 5 - 2, dx = d % 5 - 2;
                int hh = h + dy, ww = w + dx;
                bool ok = (hh >= 0) & (hh < IMG) & (ww >= 0) & (ww < IMG);
                float wf = ok ? wp[d] : 0.f;
                const unsigned short* vp = vb + (ok ? (dy * IMG + dx) * YSTR : 0);
                ushort8 vv = *(const ushort8*)vp;
#pragma unroll
                for (int j = 0; j < 8; ++j)
                    acc[j] += wf * bf2f(vv[j]);
            }
        }
        unsigned short* fo = fold + (size_t)rem * NC + head * 32 + q8 * 8;
        ushort8 ov;
#pragma unroll
        for (int j = 0; j < 8; ++j) ov[j] = f2bf(acc[j]);
        *(ushort8*)fo = ov;
    }
}

extern "C" void kernel_launch(void* const* d_in, const int* in_sizes, int n_in,
                              void* d_out, int out_size, void* d_ws, size_t ws_size,
                              hipStream_t stream)
{
    const float* x  = (const float*)d_in[0];
    const float* Wv = (const float*)d_in[1];
    const float* Wa = (const float*)d_in[2];
    const float* ba = (const float*)d_in[3];
    const float* Wp = (const float*)d_in[4];
    const float* bp = (const float*)d_in[5];
    float* out = (float*)d_out;

    unsigned short* xt    = (unsigned short*)d_ws;       // 50176*192 (reused as fold)
    unsigned short* Y     = xt + 9633792;                // 50176*768
    unsigned short* Wall  = Y + 38535168;                // 768*192
    unsigned short* Wpt   = Wall + 147456;               // 192*192
    float*          ball  = (float*)(Wpt + 36864);       // 768 floats
    unsigned short* foldb = xt;                          // xt dead after gemm_big

    dim3 blk(256);
    prep_weights<<<576, blk, 0, stream>>>(Wv, Wa, Wp, ba, Wall, Wpt, ball);
    transpose_x<<<dim3(784, 3), blk, 0, stream>>>(x, xt);
    gemm_big<<<dim3(6, 392), blk, 0, stream>>>(xt, Wall, ball, Y);
    fused_att_agg<<<1568, blk, 0, stream>>>(Y, foldb);
    gemm_small<<<dim3(196, 3), blk, 0, stream>>>(Wpt, foldb, bp, out);
}

// Round 12
// 194.921 us; speedup vs baseline: 1.1528x; 1.0772x over previous
//
#include <hip/hip_runtime.h>
#include <hip/hip_bf16.h>
#include <math.h>

#define HW 3136
#define NC 192
#define NHEADS 6
#define IMG 56
#define NATT 486
#define YSTR 768           // Y row: [0,192)=v, [192,768)=att head*96 + k*10 + l
#define ATT_SCALE 0.17677669529663687f  // 32^-0.5

typedef __attribute__((ext_vector_type(8))) short short8;
typedef __attribute__((ext_vector_type(8))) unsigned short ushort8;
typedef __attribute__((ext_vector_type(4))) float float4v;

__device__ __forceinline__ float bf2f(unsigned short u) {
    unsigned int x = ((unsigned int)u) << 16;
    return __builtin_bit_cast(float, x);
}
__device__ __forceinline__ unsigned short f2bf(float f) {
    __hip_bfloat16 h = __float2bfloat16(f);
    return __builtin_bit_cast(unsigned short, h);
}
__device__ __forceinline__ void gload_lds16(const void* g, void* l) {
    __builtin_amdgcn_global_load_lds((const __attribute__((address_space(1))) void*)g,
                                     (__attribute__((address_space(3))) void*)l, 16, 0, 0);
}

// x [16][192][3136] fp32 -> xt [50176][192] bf16 (channels-last). grid (784,3), block 256.
__global__ __launch_bounds__(256) void transpose_x(const float* __restrict__ x,
                                                   unsigned short* __restrict__ xt)
{
    __shared__ float tile[64][65];
    int bx = blockIdx.x;
    int n = (bx * 64) / HW;
    int hw0 = (bx * 64) % HW;
    int c0 = blockIdx.y * 64;
    int tl = threadIdx.x & 63, tg = threadIdx.x >> 6;
    const float* xn = x + (size_t)n * NC * HW;
#pragma unroll
    for (int i = 0; i < 16; ++i)
        tile[tg * 16 + i][tl] = xn[(size_t)(c0 + tg * 16 + i) * HW + hw0 + tl];
    __syncthreads();
    unsigned short* xp = xt + ((size_t)n * HW + hw0) * NC + c0;
#pragma unroll
    for (int i = 0; i < 16; ++i) {
        int hwr = tg * 16 + i;
        xp[(size_t)hwr * NC + tl] = f2bf(tile[tl][hwr]);
    }
}

// Weight prep: Wall[768][192] = [Wv^T ; Wa^T permuted, stride 10], ball[768],
// Wpt[192][192] = Wp^T. grid 576, block 256.
__global__ __launch_bounds__(256) void prep_weights(
    const float* __restrict__ Wv, const float* __restrict__ Wa, const float* __restrict__ Wp,
    const float* __restrict__ ba,
    unsigned short* __restrict__ Wall, unsigned short* __restrict__ Wpt,
    float* __restrict__ ball)
{
    int idx = blockIdx.x * 256 + threadIdx.x;
    if (idx < 36864) {
        int d = idx / 192, k = idx - d * 192;
        Wpt[idx] = f2bf(Wp[(size_t)k * NC + d]);
    }
    if (idx < 147456) {                       // 768*192
        int d = idx / 192, k = idx - d * 192;
        unsigned short val;
        float bv = 0.f;
        if (d < 192) {
            val = f2bf(Wv[(size_t)k * NC + d]);
        } else {
            int dp = d - 192;                 // 0..575
            int head = dp / 96, rr = dp - head * 96;
            int k9 = rr / 10, l = rr - k9 * 10;
            bool valid = (k9 < 9) && (l < 9);
            int src = head * 81 + k9 * 9 + l;
            val = valid ? f2bf(Wa[(size_t)k * NATT + src]) : (unsigned short)0;
            bv = valid ? ba[src] : 0.f;
        }
        Wall[idx] = val;
        if (k == 0) ball[d] = bv;
    }
}

// Y[row][col] = sum_k xt[row][k]*Wall[col][k] + ball[col], bf16 out.
// 128x128 tile, 4 waves of 64x64 (4x4 acc), K=192 in 6 dbuf steps, glds16 staging.
// grid (6, 392).
__global__ __launch_bounds__(256) void gemm_big(
    const unsigned short* __restrict__ A, const unsigned short* __restrict__ W,
    const float* __restrict__ ball, unsigned short* __restrict__ Y)
{
    __shared__ __align__(16) unsigned short As[2][4096];
    __shared__ __align__(16) unsigned short Bs[2][4096];
    int t = threadIdx.x, lane = t & 63, wave = t >> 6;
    int col0 = blockIdx.x * 128, row0 = blockIdx.y * 128;
    int fr = lane & 15, fq = lane >> 4;
    int wm = (wave >> 1) * 64, wn = (wave & 1) * 64;
    int srow = lane >> 2;          // 0..15
    int soff = (lane & 3) * 16;    // byte offset within a 64-B k-row chunk
    const char* Ab = (const char*)A;
    const char* Wb = (const char*)W;

    float4v acc[4][4] = {};

#define STAGE_BIG(buf, k0)                                                        \
    {                                                                             \
        _Pragma("unroll")                                                         \
        for (int i = 0; i < 2; ++i) {                                             \
            int j = wave * 2 + i;                                                 \
            gload_lds16(Ab + (size_t)(row0 + j * 16 + srow) * 384 + (k0)*2 + soff,\
                        (char*)As[buf] + j * 1024);                               \
            gload_lds16(Wb + (size_t)(col0 + j * 16 + srow) * 384 + (k0)*2 + soff,\
                        (char*)Bs[buf] + j * 1024);                               \
        }                                                                         \
    }

    STAGE_BIG(0, 0);
    for (int s = 0; s < 6; ++s) {
        if (s < 5) STAGE_BIG((s + 1) & 1, (s + 1) * 32);
        __syncthreads();
        int buf = s & 1;
        short8 af[4], bf[4];
#pragma unroll
        for (int mi = 0; mi < 4; ++mi)
            af[mi] = *(const short8*)((const char*)As[buf] + (wm + mi * 16 + fr) * 64 + fq * 16);
#pragma unroll
        for (int ni = 0; ni < 4; ++ni)
            bf[ni] = *(const short8*)((const char*)Bs[buf] + (wn + ni * 16 + fr) * 64 + fq * 16);
#pragma unroll
        for (int mi = 0; mi < 4; ++mi)
#pragma unroll
            for (int ni = 0; ni < 4; ++ni)
                acc[mi][ni] = __builtin_amdgcn_mfma_f32_16x16x32_bf16(
                    af[mi], bf[ni], acc[mi][ni], 0, 0, 0);
        __syncthreads();
    }

#pragma unroll
    for (int ni = 0; ni < 4; ++ni) {
        int col = col0 + wn + ni * 16 + fr;
        float b = ball[col];
#pragma unroll
        for (int mi = 0; mi < 4; ++mi) {
            int row = row0 + wm + mi * 16 + fq * 4;
#pragma unroll
            for (int r = 0; r < 4; ++r)
                Y[(size_t)(row + r) * YSTR + col] = f2bf(acc[mi][ni][r] + b);
        }
    }
#undef STAGE_BIG
}

// out[img][m][phw] = sum_k Wpt[m][k]*fold[n][k] + bias[m]; 64(m) x 256(n) tile.
// grid (196, 3), block 256, 4 waves each 64x64.
__global__ __launch_bounds__(256) void gemm_small(
    const unsigned short* __restrict__ A,   // Wpt [192][192]
    const unsigned short* __restrict__ B,   // fold [50176][192]
    const float* __restrict__ bias, float* __restrict__ out)
{
    __shared__ __align__(16) unsigned short As[2][2048];
    __shared__ __align__(16) unsigned short Bs[2][8192];
    int t = threadIdx.x, lane = t & 63, wave = t >> 6;
    int n0 = blockIdx.x * 256, m0 = blockIdx.y * 64;
    int fr = lane & 15, fq = lane >> 4;
    int srow = lane >> 2, soff = (lane & 3) * 16;
    const char* Ab = (const char*)A;
    const char* Bb = (const char*)B;

    float4v acc[4][4] = {};

#define STAGE_SMALL(buf, k0)                                                      \
    {                                                                             \
        gload_lds16(Ab + (size_t)(m0 + wave * 16 + srow) * 384 + (k0)*2 + soff,   \
                    (char*)As[buf] + wave * 1024);                                \
        _Pragma("unroll")                                                         \
        for (int i = 0; i < 4; ++i) {                                             \
            int j = wave * 4 + i;                                                 \
            gload_lds16(Bb + (size_t)(n0 + j * 16 + srow) * 384 + (k0)*2 + soff,  \
                        (char*)Bs[buf] + j * 1024);                               \
        }                                                                         \
    }

    STAGE_SMALL(0, 0);
    for (int s = 0; s < 6; ++s) {
        if (s < 5) STAGE_SMALL((s + 1) & 1, (s + 1) * 32);
        __syncthreads();
        int buf = s & 1;
        short8 af[4], bf[4];
#pragma unroll
        for (int mi = 0; mi < 4; ++mi)
            af[mi] = *(const short8*)((const char*)As[buf] + (mi * 16 + fr) * 64 + fq * 16);
#pragma unroll
        for (int ni = 0; ni < 4; ++ni)
            bf[ni] = *(const short8*)((const char*)Bs[buf] + (wave * 64 + ni * 16 + fr) * 64 + fq * 16);
#pragma unroll
        for (int mi = 0; mi < 4; ++mi)
#pragma unroll
            for (int ni = 0; ni < 4; ++ni)
                acc[mi][ni] = __builtin_amdgcn_mfma_f32_16x16x32_bf16(
                    af[mi], bf[ni], acc[mi][ni], 0, 0, 0);
        __syncthreads();
    }

#pragma unroll
    for (int ni = 0; ni < 4; ++ni) {
        int n = n0 + wave * 64 + ni * 16 + fr;
        int img = n / HW, phw = n - img * HW;
        float* op = out + (size_t)img * (NC * HW) + phw;
#pragma unroll
        for (int mi = 0; mi < 4; ++mi) {
            int m = m0 + mi * 16 + fq * 4;
#pragma unroll
            for (int r = 0; r < 4; ++r)
                op[(size_t)(m + r) * HW] = acc[mi][ni][r] + bias[m + r];
        }
    }
#undef STAGE_SMALL
}

// Fused softmax + weight-combine + aggregation, v4: LDS v-halo.
// Block = one head x (8x28) image tile (224 positions).
//  - stage zero-padded 12x32x32ch v-halo to LDS (96 B/thread, coalesced 16-B)
//  - threads 0..223: full softmax per position -> wc[25] to LDS
//  - phase 2: 896 items (pos, ch-quarter), ALL v reads from LDS, no bounds.
__global__ __launch_bounds__(256) void fused_att_agg(
    const unsigned short* __restrict__ Y, unsigned short* __restrict__ fold)
{
    __shared__ __align__(16) unsigned short vt[12 * 32 * 32];   // 24576 B [vrow][vcol][ch]
    __shared__ float swc[224 * 25];                             // 22400 B
    int t = threadIdx.x;
    int bid = blockIdx.x;
    int head = bid % NHEADS; int tmp = bid / NHEADS;
    int tcol = tmp & 1; tmp >>= 1;
    int trow = tmp % 7; int img = tmp / 7;
    int h0 = trow * 8, w0 = tcol * 28;

    // ---- stage v halo (zero-padded borders) ----
    {
        const unsigned short* Yv = Y + head * 32;
#pragma unroll
        for (int i = 0; i < 6; ++i) {
            int u = i * 256 + t;                 // 0..1535
            int slot = u >> 2, q = u & 3;        // slot = vrow*32+vcol, q = 16-B quarter
            int vrow = slot >> 5, vcol = slot & 31;
            int hh = h0 - 2 + vrow, ww = w0 - 2 + vcol;
            bool ok = (hh >= 0) & (hh < IMG) & (ww >= 0) & (ww < IMG);
            ushort8 val = {};
            if (ok)
                val = *(const ushort8*)(Yv + (size_t)(img * HW + hh * IMG + ww) * YSTR + q * 8);
            *(ushort8*)&vt[(size_t)slot * 32 + q * 8] = val;
        }
    }

    // ---- softmax -> stencil weights (threads 0..223) ----
    if (t < 224) {
        int ph = t / 28, pw = t - (t / 28) * 28;
        int h = h0 + ph, w = w0 + pw;
        const unsigned short* attn =
            Y + (size_t)(img * HW + h * IMG + w) * YSTR + 192 + head * 96;
        float wc[25];
#pragma unroll
        for (int d = 0; d < 25; ++d) wc[d] = 0.f;
#pragma unroll
        for (int k = 0; k < 9; ++k) {
            const int oky = k / 3 - 1, okx = k % 3 - 1;
            int hh = h - oky, ww = w - okx;
            if (hh < 0 || hh >= IMG || ww < 0 || ww >= IMG) continue;
            const unsigned short* ap = attn - (ptrdiff_t)(oky * IMG + okx) * YSTR + k * 10;
            ushort8 a8;
            __builtin_memcpy(&a8, ap, 16);       // 4-B aligned
            float a[9];
#pragma unroll
            for (int l = 0; l < 8; ++l) a[l] = bf2f(a8[l]);
            a[8] = bf2f(ap[8]);
            float m = -1e30f;
#pragma unroll
            for (int l = 0; l < 9; ++l) m = fmaxf(m, a[l]);
            float s = 0.f;
#pragma unroll
            for (int l = 0; l < 9; ++l) {
                a[l] = __expf((a[l] - m) * ATT_SCALE);
                s += a[l];
            }
            float r = 1.f / s;
#pragma unroll
            for (int l = 0; l < 9; ++l) {
                const int dy = (l / 3 - 1) - oky + 2;
                const int dx = (l % 3 - 1) - okx + 2;
                wc[dy * 5 + dx] += a[l] * r;
            }
        }
        float* o = swc + t * 25;
#pragma unroll
        for (int d = 0; d < 25; ++d) o[d] = wc[d];
    }
    __syncthreads();

    // ---- phase 2: aggregate from LDS (no bounds checks) ----
#pragma unroll
    for (int i = 0; i < 4; ++i) {
        int item = i * 256 + t;                  // 0..895
        if (item < 896) {
            int p = item >> 2, q8 = item & 3;
            int ph = p / 28, pw = p - (p / 28) * 28;
            const float* wp = swc + p * 25;
            float acc[8];
#pragma unroll
            for (int j = 0; j < 8; ++j) acc[j] = 0.f;
#pragma unroll
            for (int d = 0; d < 25; ++d) {
                const int dy = d / 5, dx = d % 5;    // 0..4 (halo-shifted)
                float wf = wp[d];
                ushort8 vv = *(const ushort8*)&vt[(((ph + dy) << 5) + (pw + dx)) * 32 + q8 * 8];
#pragma unroll
                for (int j = 0; j < 8; ++j)
                    acc[j] += wf * bf2f(vv[j]);
            }
            int rem = img * HW + (h0 + ph) * IMG + (w0 + pw);
            unsigned short* fo = fold + (size_t)rem * NC + head * 32 + q8 * 8;
            ushort8 ov;
#pragma unroll
            for (int j = 0; j < 8; ++j) ov[j] = f2bf(acc[j]);
            *(ushort8*)fo = ov;
        }
    }
}

extern "C" void kernel_launch(void* const* d_in, const int* in_sizes, int n_in,
                              void* d_out, int out_size, void* d_ws, size_t ws_size,
                              hipStream_t stream)
{
    const float* x  = (const float*)d_in[0];
    const float* Wv = (const float*)d_in[1];
    const float* Wa = (const float*)d_in[2];
    const float* ba = (const float*)d_in[3];
    const float* Wp = (const float*)d_in[4];
    const float* bp = (const float*)d_in[5];
    float* out = (float*)d_out;

    unsigned short* xt    = (unsigned short*)d_ws;       // 50176*192 (reused as fold)
    unsigned short* Y     = xt + 9633792;                // 50176*768
    unsigned short* Wall  = Y + 38535168;                // 768*192
    unsigned short* Wpt   = Wall + 147456;               // 192*192
    float*          ball  = (float*)(Wpt + 36864);       // 768 floats
    unsigned short* foldb = xt;                          // xt dead after gemm_big

    dim3 blk(256);
    prep_weights<<<576, blk, 0, stream>>>(Wv, Wa, Wp, ba, Wall, Wpt, ball);
    transpose_x<<<dim3(784, 3), blk, 0, stream>>>(x, xt);
    gemm_big<<<dim3(6, 392), blk, 0, stream>>>(xt, Wall, ball, Y);
    fused_att_agg<<<1344, blk, 0, stream>>>(Y, foldb);   // 16 img x 7 x 2 tiles x 6 heads
    gemm_small<<<dim3(196, 3), blk, 0, stream>>>(Wpt, foldb, bp, out);
}